// Round 5
// baseline (17377.701 us; speedup 1.0000x reference)
//
#include <hip/hip_runtime.h>
#include <math.h>

#define N_WORDS 16384
#define MAX_CHARS 16
#define CE 32
#define H1 64
#define WE 64
#define H2 128
#define N_TAGS 64

typedef _Float16 f16x8 __attribute__((ext_vector_type(8)));
typedef float f32x4 __attribute__((ext_vector_type(4)));

__device__ __forceinline__ float sigf(float x) { return 1.0f / (1.0f + __expf(-x)); }
__device__ __forceinline__ float tanh_fast(float x) {
    float xc = fminf(fmaxf(x, -15.f), 15.f);
    float e = __expf(2.f * xc);
    return 1.f - 2.f / (e + 1.f);
}
__device__ __forceinline__ float extq(f32x4 a, int q) {
    return (q == 0) ? a[0] : (q == 1) ? a[1] : (q == 2) ? a[2] : a[3];
}

// ---------------- Kernel 1: char LSTM, one wave per word, 16 words/block ----
extern "C" __global__ void __launch_bounds__(1024)
char_lstm_kernel(const int* __restrict__ char_ids, const int* __restrict__ char_lens,
                 const float* __restrict__ char_emb,
                 const float* __restrict__ Wih1, const float* __restrict__ Whh1,
                 const float* __restrict__ bih1, const float* __restrict__ bhh1,
                 float* __restrict__ h_char)
{
    extern __shared__ float lds[];
    float* Wc = lds;               // 256*97
    float* b1 = Wc + 256 * 97;     // 256
    float* xh = b1 + 256;          // 16*97
    const int tid = threadIdx.x;

    for (int idx = tid; idx < 256 * 96; idx += 1024) {
        int r = idx / 96, k = idx - r * 96;
        float v = (k < CE) ? Wih1[r * CE + k] : Whh1[r * H1 + (k - CE)];
        Wc[r * 97 + k] = v;
    }
    for (int r = tid; r < 256; r += 1024) b1[r] = bih1[r] + bhh1[r];
    __syncthreads();

    const int wlocal = tid >> 6;   // 0..15
    const int lane   = tid & 63;
    const int word   = blockIdx.x * 16 + wlocal;
    const int len    = char_lens[word];
    float h = 0.f, c = 0.f;
    float* xhw = xh + wlocal * 97;

    for (int t = 0; t < MAX_CHARS; ++t) {
        int cid = char_ids[word * MAX_CHARS + t];
        if (lane < CE) xhw[lane] = char_emb[cid * CE + lane];
        xhw[CE + lane] = h;
        __syncthreads();

        float a0 = 0.f, a1 = 0.f, a2 = 0.f, a3 = 0.f;
        const float* w0 = Wc + (0 * 64 + lane) * 97;
        const float* w1 = Wc + (1 * 64 + lane) * 97;
        const float* w2 = Wc + (2 * 64 + lane) * 97;
        const float* w3 = Wc + (3 * 64 + lane) * 97;
        #pragma unroll 8
        for (int k = 0; k < 96; ++k) {
            float x = xhw[k];
            a0 += w0[k] * x; a1 += w1[k] * x; a2 += w2[k] * x; a3 += w3[k] * x;
        }
        float pi = a0 + b1[lane];
        float pf = a1 + b1[64 + lane];
        float pg = a2 + b1[128 + lane];
        float po = a3 + b1[192 + lane];
        if (t < len) {
            float ig = sigf(pi), fg = sigf(pf), gg = tanhf(pg), og = sigf(po);
            c = fg * c + ig * gg;
            h = og * tanhf(c);
        }
        __syncthreads();
    }
    h_char[word * H1 + lane] = h;
}

// ---------------- Kernel 2: xpre = [word_emb | h_char] @ Wih2^T + b2 --------
// OUTPUT TRANSPOSED for kernel 3: xpre_t[t][hid*4 + g]  (g = col>>7, hid = col&127)
extern "C" __global__ void __launch_bounds__(256)
xpre_gemm_kernel(const int* __restrict__ word_ids, const float* __restrict__ word_emb,
                 const float* __restrict__ h_char,
                 const float* __restrict__ Wih2,
                 const float* __restrict__ bih2, const float* __restrict__ bhh2,
                 float* __restrict__ xpre)
{
    __shared__ float Wl[64 * 130];
    __shared__ float Xl[32 * 130];
    const int tid = threadIdx.x;
    const int wb = blockIdx.x * 32;   // word base
    const int cb = blockIdx.y * 64;   // col base

    for (int idx = tid; idx < 64 * 128; idx += 256) {
        int r = idx >> 7, k = idx & 127;
        Wl[r * 130 + k] = Wih2[(cb + r) * H2 + k];
    }
    for (int idx = tid; idx < 32 * 128; idx += 256) {
        int w = idx >> 7, k = idx & 127;
        float v = (k < WE) ? word_emb[(long)word_ids[wb + w] * WE + k]
                           : h_char[(long)(wb + w) * H1 + (k - WE)];
        Xl[w * 130 + k] = v;
    }
    __syncthreads();

    const int tc = tid & 31;
    const int wg = tid >> 5;          // 0..7
    float acc[4][2] = {};
    for (int k = 0; k < 128; ++k) {
        float wv0 = Wl[tc * 130 + k];
        float wv1 = Wl[(tc + 32) * 130 + k];
        #pragma unroll
        for (int i = 0; i < 4; ++i) {
            float x = Xl[(wg * 4 + i) * 130 + k];
            acc[i][0] += x * wv0;
            acc[i][1] += x * wv1;
        }
    }
    int c0 = cb + tc, c1 = cb + tc + 32;
    float b0 = bih2[c0] + bhh2[c0];
    float b1v = bih2[c1] + bhh2[c1];
    int o0 = (c0 & 127) * 4 + (c0 >> 7);
    int o1 = (c1 & 127) * 4 + (c1 >> 7);
    #pragma unroll
    for (int i = 0; i < 4; ++i) {
        long w = wb + wg * 4 + i;
        xpre[w * 512 + o0] = acc[i][0] + b0;
        xpre[w * 512 + o1] = acc[i][1] + b1v;
    }
}

// ---------------- Kernel 3: sequential word LSTM via f16 MFMA, 4 waves -----
// Wave w owns rows [32w, 32w+32) = 2 row-tiles per gate. 32 MFMA/wave/step
// (same 128/step chip-wide as before, half the VALU issue). kc-major order so
// bf[1..3] ds_reads hide under MFMA issue. Raw s_barrier, lgkmcnt-only drain.
extern "C" __global__ void __launch_bounds__(256, 1)
word_lstm_kernel(const float* __restrict__ xpre, const float* __restrict__ Whh2,
                 float* __restrict__ hs)
{
    __shared__ _Float16 h_lds[2][128];
    const int tid = threadIdx.x;
    const int w   = tid >> 6;      // wave 0..3
    const int l   = tid & 63;
    const int lg  = l >> 4;        // k-subgroup / rowgroup 0..3
    const int lr  = l & 15;        // A-operand row-in-tile
    const int q   = l & 3;         // accumulator reg select (q == lr&3)
    const int hidx0 = 32 * w + (lg << 2) + q;   // tile-0 h row
    const int hidx1 = hidx0 + 16;               // tile-1 h row

    // A-fragments: af[gate][T][kc], elem j = Whh2[g*128+32w+16T+lr][kc*32+lg*8+j]
    f16x8 af[4][2][4];
    #pragma unroll
    for (int g = 0; g < 4; ++g)
        #pragma unroll
        for (int T = 0; T < 2; ++T) {
            const float* wrow = Whh2 + (size_t)(g * 128 + 32 * w + 16 * T + lr) * 128;
            #pragma unroll
            for (int kc = 0; kc < 4; ++kc) {
                const float* src = wrow + kc * 32 + lg * 8;
                float4 v0 = *(const float4*)src;
                float4 v1 = *(const float4*)(src + 4);
                f16x8 a;
                a[0] = (_Float16)v0.x; a[1] = (_Float16)v0.y;
                a[2] = (_Float16)v0.z; a[3] = (_Float16)v0.w;
                a[4] = (_Float16)v1.x; a[5] = (_Float16)v1.y;
                a[6] = (_Float16)v1.z; a[7] = (_Float16)v1.w;
                af[g][T][kc] = a;
            }
        }
    if (tid < 128) h_lds[0][tid] = (_Float16)0.f;
    float c0 = 0.f, c1 = 0.f;
    float4 xp0 = *(const float4*)(xpre + hidx0 * 4);   // t = 0 (transposed)
    float4 xp1 = *(const float4*)(xpre + hidx1 * 4);
    float hbuf0[8], hbuf1[8];
    __syncthreads();

    for (int t8 = 0; t8 < N_WORDS / 8; ++t8) {
        #pragma unroll
        for (int j = 0; j < 8; ++j) {
            const int t = t8 * 8 + j;
            const int tn = (t + 1) & (N_WORDS - 1);
            // independent global prefetch first — stays in flight across barrier
            float4 xpn0 = *(const float4*)(xpre + (size_t)tn * 512 + hidx0 * 4);
            float4 xpn1 = *(const float4*)(xpre + (size_t)tn * 512 + hidx1 * 4);

            const _Float16* hb = h_lds[j & 1];
            f16x8 bf[4];
            #pragma unroll
            for (int kc = 0; kc < 4; ++kc)
                bf[kc] = *(const f16x8*)(hb + kc * 32 + lg * 8);

            f32x4 acc0[4], acc1[4];
            #pragma unroll
            for (int g = 0; g < 4; ++g) {
                acc0[g] = (f32x4){0.f, 0.f, 0.f, 0.f};
                acc1[g] = (f32x4){0.f, 0.f, 0.f, 0.f};
            }
            // kc-major: first MFMA needs only bf[0]; 8 independent chains
            #pragma unroll
            for (int kc = 0; kc < 4; ++kc) {
                #pragma unroll
                for (int g = 0; g < 4; ++g) {
                    acc0[g] = __builtin_amdgcn_mfma_f32_16x16x32_f16(
                        af[g][0][kc], bf[kc], acc0[g], 0, 0, 0);
                    acc1[g] = __builtin_amdgcn_mfma_f32_16x16x32_f16(
                        af[g][1][kc], bf[kc], acc1[g], 0, 0, 0);
                }
            }
            // tile 0 gates
            float p00 = extq(acc0[0], q) + xp0.x;
            float p01 = extq(acc0[1], q) + xp0.y;
            float p02 = extq(acc0[2], q) + xp0.z;
            float p03 = extq(acc0[3], q) + xp0.w;
            float ig0 = sigf(p00), fg0 = sigf(p01);
            float gg0 = tanh_fast(p02), og0 = sigf(p03);
            c0 = fg0 * c0 + ig0 * gg0;
            float hn0 = og0 * tanh_fast(c0);
            // tile 1 gates
            float p10 = extq(acc1[0], q) + xp1.x;
            float p11 = extq(acc1[1], q) + xp1.y;
            float p12 = extq(acc1[2], q) + xp1.z;
            float p13 = extq(acc1[3], q) + xp1.w;
            float ig1 = sigf(p10), fg1 = sigf(p11);
            float gg1 = tanh_fast(p12), og1 = sigf(p13);
            c1 = fg1 * c1 + ig1 * gg1;
            float hn1 = og1 * tanh_fast(c1);

            hbuf0[j] = hn0;
            hbuf1[j] = hn1;
            if (lr < 4) {
                h_lds[(j + 1) & 1][hidx0] = (_Float16)hn0;
                h_lds[(j + 1) & 1][hidx1] = (_Float16)hn1;
            }
            xp0 = xpn0;
            xp1 = xpn1;

            asm volatile("s_waitcnt lgkmcnt(0)" ::: "memory");
            __builtin_amdgcn_sched_barrier(0);
            __builtin_amdgcn_s_barrier();
            __builtin_amdgcn_sched_barrier(0);
        }
        // stores overlap the next step's ds_read latency
        if (lr < 4) {
            #pragma unroll
            for (int jj = 0; jj < 8; ++jj) {
                hs[(size_t)(t8 * 8 + jj) * 128 + hidx0] = hbuf0[jj];
                hs[(size_t)(t8 * 8 + jj) * 128 + hidx1] = hbuf1[jj];
            }
        }
    }
}

// ---------------- Kernel 4: logits + log_softmax, wave per word ------------
extern "C" __global__ void __launch_bounds__(256)
tag_kernel(const float* __restrict__ hs, const float* __restrict__ Wtag,
           const float* __restrict__ btag, float* __restrict__ out)
{
    __shared__ float Wl[64 * 129];
    const int tid = threadIdx.x;
    for (int idx = tid; idx < 64 * 128; idx += 256) {
        int r = idx >> 7, k = idx & 127;
        Wl[r * 129 + k] = Wtag[r * H2 + k];
    }
    __syncthreads();

    const int lane = tid & 63;
    const int word = blockIdx.x * 4 + (tid >> 6);
    const float* hrow = hs + (long)word * H2;
    float acc = btag[lane];
    #pragma unroll 4
    for (int k = 0; k < 128; ++k) acc += Wl[lane * 129 + k] * hrow[k];

    float m = acc;
    #pragma unroll
    for (int off = 32; off > 0; off >>= 1) m = fmaxf(m, __shfl_xor(m, off));
    float e = expf(acc - m);
    float s = e;
    #pragma unroll
    for (int off = 32; off > 0; off >>= 1) s += __shfl_xor(s, off);
    out[(long)word * N_TAGS + lane] = acc - m - logf(s);
}

extern "C" void kernel_launch(void* const* d_in, const int* in_sizes, int n_in,
                              void* d_out, int out_size, void* d_ws, size_t ws_size,
                              hipStream_t stream)
{
    (void)in_sizes; (void)n_in; (void)out_size; (void)ws_size;
    const int*   char_ids  = (const int*)d_in[0];
    const int*   word_ids  = (const int*)d_in[1];
    const int*   char_lens = (const int*)d_in[2];
    const float* char_emb  = (const float*)d_in[3];
    const float* word_emb  = (const float*)d_in[4];
    const float* Wih1 = (const float*)d_in[5];
    const float* Whh1 = (const float*)d_in[6];
    const float* bih1 = (const float*)d_in[7];
    const float* bhh1 = (const float*)d_in[8];
    const float* Wih2 = (const float*)d_in[9];
    const float* Whh2 = (const float*)d_in[10];
    const float* bih2 = (const float*)d_in[11];
    const float* bhh2 = (const float*)d_in[12];
    const float* Wtag = (const float*)d_in[13];
    const float* btag = (const float*)d_in[14];
    float* out = (float*)d_out;

    float* h_char = (float*)d_ws;                          // 16384*64
    float* xpre   = h_char + (size_t)N_WORDS * H1;         // 16384*512 (transposed)
    float* hs     = xpre + (size_t)N_WORDS * 512;          // 16384*128

    const int k1_lds = (256 * 97 + 256 + 16 * 97) * 4;     // 106560 B
    hipFuncSetAttribute((const void*)char_lstm_kernel,
                        hipFuncAttributeMaxDynamicSharedMemorySize, k1_lds);

    char_lstm_kernel<<<N_WORDS / 16, 1024, k1_lds, stream>>>(
        char_ids, char_lens, char_emb, Wih1, Whh1, bih1, bhh1, h_char);

    dim3 g2(N_WORDS / 32, 8);
    xpre_gemm_kernel<<<g2, 256, 0, stream>>>(
        word_ids, word_emb, h_char, Wih2, bih2, bhh2, xpre);

    word_lstm_kernel<<<1, 256, 0, stream>>>(xpre, Whh2, hs);

    tag_kernel<<<N_WORDS / 4, 256, 0, stream>>>(hs, Wtag, btag, out);
}

// Round 6
// 10692.243 us; speedup vs baseline: 1.6253x; 1.6253x over previous
//
#include <hip/hip_runtime.h>
#include <math.h>

#define N_WORDS 16384
#define MAX_CHARS 16
#define CE 32
#define H1 64
#define WE 64
#define H2 128
#define N_TAGS 64

typedef _Float16 f16x8 __attribute__((ext_vector_type(8)));
typedef float f32x4 __attribute__((ext_vector_type(4)));
typedef int i32x8 __attribute__((ext_vector_type(8)));

__device__ __forceinline__ float sigf(float x) { return 1.0f / (1.0f + __expf(-x)); }
__device__ __forceinline__ float tanh_fast(float x) {
    float xc = fminf(fmaxf(x, -15.f), 15.f);
    float e = __expf(2.f * xc);
    return 1.f - 2.f / (e + 1.f);
}
__device__ __forceinline__ float extq(f32x4 a, int q) {
    return (q == 0) ? a[0] : (q == 1) ? a[1] : (q == 2) ? a[2] : a[3];
}

// ---------------- Kernel 1: char LSTM, one wave per word, 16 words/block ----
extern "C" __global__ void __launch_bounds__(1024)
char_lstm_kernel(const int* __restrict__ char_ids, const int* __restrict__ char_lens,
                 const float* __restrict__ char_emb,
                 const float* __restrict__ Wih1, const float* __restrict__ Whh1,
                 const float* __restrict__ bih1, const float* __restrict__ bhh1,
                 float* __restrict__ h_char)
{
    extern __shared__ float lds[];
    float* Wc = lds;               // 256*97
    float* b1 = Wc + 256 * 97;     // 256
    float* xh = b1 + 256;          // 16*97
    const int tid = threadIdx.x;

    for (int idx = tid; idx < 256 * 96; idx += 1024) {
        int r = idx / 96, k = idx - r * 96;
        float v = (k < CE) ? Wih1[r * CE + k] : Whh1[r * H1 + (k - CE)];
        Wc[r * 97 + k] = v;
    }
    for (int r = tid; r < 256; r += 1024) b1[r] = bih1[r] + bhh1[r];
    __syncthreads();

    const int wlocal = tid >> 6;   // 0..15
    const int lane   = tid & 63;
    const int word   = blockIdx.x * 16 + wlocal;
    const int len    = char_lens[word];
    float h = 0.f, c = 0.f;
    float* xhw = xh + wlocal * 97;

    for (int t = 0; t < MAX_CHARS; ++t) {
        int cid = char_ids[word * MAX_CHARS + t];
        if (lane < CE) xhw[lane] = char_emb[cid * CE + lane];
        xhw[CE + lane] = h;
        __syncthreads();

        float a0 = 0.f, a1 = 0.f, a2 = 0.f, a3 = 0.f;
        const float* w0 = Wc + (0 * 64 + lane) * 97;
        const float* w1 = Wc + (1 * 64 + lane) * 97;
        const float* w2 = Wc + (2 * 64 + lane) * 97;
        const float* w3 = Wc + (3 * 64 + lane) * 97;
        #pragma unroll 8
        for (int k = 0; k < 96; ++k) {
            float x = xhw[k];
            a0 += w0[k] * x; a1 += w1[k] * x; a2 += w2[k] * x; a3 += w3[k] * x;
        }
        float pi = a0 + b1[lane];
        float pf = a1 + b1[64 + lane];
        float pg = a2 + b1[128 + lane];
        float po = a3 + b1[192 + lane];
        if (t < len) {
            float ig = sigf(pi), fg = sigf(pf), gg = tanhf(pg), og = sigf(po);
            c = fg * c + ig * gg;
            h = og * tanhf(c);
        }
        __syncthreads();
    }
    h_char[word * H1 + lane] = h;
}

// ---------------- Kernel 2: xpre = [word_emb | h_char] @ Wih2^T + b2 --------
// OUTPUT TRANSPOSED for kernel 3: xpre_t[t][hid*4 + g]  (g = col>>7, hid = col&127)
extern "C" __global__ void __launch_bounds__(256)
xpre_gemm_kernel(const int* __restrict__ word_ids, const float* __restrict__ word_emb,
                 const float* __restrict__ h_char,
                 const float* __restrict__ Wih2,
                 const float* __restrict__ bih2, const float* __restrict__ bhh2,
                 float* __restrict__ xpre)
{
    __shared__ float Wl[64 * 130];
    __shared__ float Xl[32 * 130];
    const int tid = threadIdx.x;
    const int wb = blockIdx.x * 32;   // word base
    const int cb = blockIdx.y * 64;   // col base

    for (int idx = tid; idx < 64 * 128; idx += 256) {
        int r = idx >> 7, k = idx & 127;
        Wl[r * 130 + k] = Wih2[(cb + r) * H2 + k];
    }
    for (int idx = tid; idx < 32 * 128; idx += 256) {
        int w = idx >> 7, k = idx & 127;
        float v = (k < WE) ? word_emb[(long)word_ids[wb + w] * WE + k]
                           : h_char[(long)(wb + w) * H1 + (k - WE)];
        Xl[w * 130 + k] = v;
    }
    __syncthreads();

    const int tc = tid & 31;
    const int wg = tid >> 5;          // 0..7
    float acc[4][2] = {};
    for (int k = 0; k < 128; ++k) {
        float wv0 = Wl[tc * 130 + k];
        float wv1 = Wl[(tc + 32) * 130 + k];
        #pragma unroll
        for (int i = 0; i < 4; ++i) {
            float x = Xl[(wg * 4 + i) * 130 + k];
            acc[i][0] += x * wv0;
            acc[i][1] += x * wv1;
        }
    }
    int c0 = cb + tc, c1 = cb + tc + 32;
    float b0 = bih2[c0] + bhh2[c0];
    float b1v = bih2[c1] + bhh2[c1];
    int o0 = (c0 & 127) * 4 + (c0 >> 7);
    int o1 = (c1 & 127) * 4 + (c1 >> 7);
    #pragma unroll
    for (int i = 0; i < 4; ++i) {
        long w = wb + wg * 4 + i;
        xpre[w * 512 + o0] = acc[i][0] + b0;
        xpre[w * 512 + o1] = acc[i][1] + b1v;
    }
}

// ---------------- Kernel 3: word LSTM via fp8 K=128 scaled MFMA, 8 waves ---
// Wave w owns rows [16w,16w+16). 4 MFMAs/wave/step (one per gate), K=128 in
// one instruction. Scales fixed at E8M0 1.0 (0x7F) so scale layout is moot.
// A/B share the per-lane k-mapping -> any HW k-permutation cancels (B is a
// broadcast vector). h kept as fp8 bytes in LDS, double-buffered.
extern "C" __global__ void __launch_bounds__(512)
word_lstm_kernel(const float* __restrict__ xpre, const float* __restrict__ Whh2,
                 float* __restrict__ hs)
{
    __shared__ __align__(16) unsigned char h8[2][128];
    const int tid = threadIdx.x;
    const int w   = tid >> 6;      // wave 0..7
    const int l   = tid & 63;
    const int lg  = l >> 4;        // k-chunk 0..3 (32 bytes each)
    const int lr  = l & 15;        // A-operand row-in-tile
    const int q   = l & 3;         // accumulator reg select
    const int hidx = 16 * w + (lg << 2) + q;   // this lane's h row [0,128)

    // A-fragments fp8: af8[g] byte e = fp8(Whh2[g*128 + 16w + lr][lg*32 + e])
    i32x8 af8[4];
    #pragma unroll
    for (int g = 0; g < 4; ++g) {
        const float* wrow = Whh2 + (size_t)(g * 128 + 16 * w + lr) * 128 + lg * 32;
        i32x8 a;
        #pragma unroll
        for (int r = 0; r < 8; ++r) {
            int pk = __builtin_amdgcn_cvt_pk_fp8_f32(wrow[r * 4 + 0], wrow[r * 4 + 1], 0, false);
            pk = __builtin_amdgcn_cvt_pk_fp8_f32(wrow[r * 4 + 2], wrow[r * 4 + 3], pk, true);
            a[r] = pk;
        }
        af8[g] = a;
    }
    if (tid < 128) h8[0][tid] = 0;
    float c = 0.f;
    float4 xp = *(const float4*)(xpre + hidx * 4);   // t = 0 (transposed layout)
    float hbuf[8];
    const f32x4 zf = {0.f, 0.f, 0.f, 0.f};
    __syncthreads();

    for (int t8 = 0; t8 < N_WORDS / 8; ++t8) {
        #pragma unroll
        for (int j = 0; j < 8; ++j) {
            const int t = t8 * 8 + j;
            const int tn = (t + 1) & (N_WORDS - 1);
            // independent global prefetch — stays in flight across the barrier
            float4 xpn = *(const float4*)(xpre + (size_t)tn * 512 + hidx * 4);

            // B-fragment: 32 fp8 bytes of h, broadcast across cols
            const unsigned char* hb = h8[j & 1] + lg * 32;
            i32x8 bf = *(const i32x8*)hb;          // 2x ds_read_b128

            f32x4 acc[4];
            #pragma unroll
            for (int g = 0; g < 4; ++g)
                acc[g] = __builtin_amdgcn_mfma_scale_f32_16x16x128_f8f6f4(
                    af8[g], bf, zf, 0, 0,          // fmtA=fp8, fmtB=fp8
                    0, 0x7F7F7F7F,                 // scaleA = 1.0 everywhere
                    0, 0x7F7F7F7F);                // scaleB = 1.0 everywhere

            float p0 = extq(acc[0], q) + xp.x;
            float p1 = extq(acc[1], q) + xp.y;
            float p2 = extq(acc[2], q) + xp.z;
            float p3 = extq(acc[3], q) + xp.w;
            float ig = sigf(p0), fg = sigf(p1);
            float gg = tanh_fast(p2), og = sigf(p3);
            c = fg * c + ig * gg;
            float hn = og * tanh_fast(c);
            hbuf[j] = hn;
            if (lr < 4) {
                int hp = __builtin_amdgcn_cvt_pk_fp8_f32(hn, hn, 0, false);
                h8[(j + 1) & 1][hidx] = (unsigned char)hp;
            }
            xp = xpn;

            // raw barrier: drain LDS only, leave the global prefetch in flight
            asm volatile("s_waitcnt lgkmcnt(0)" ::: "memory");
            __builtin_amdgcn_sched_barrier(0);
            __builtin_amdgcn_s_barrier();
            __builtin_amdgcn_sched_barrier(0);
        }
        // stores overlap the next step's ds_read latency
        if (lr < 4) {
            #pragma unroll
            for (int jj = 0; jj < 8; ++jj)
                hs[(size_t)(t8 * 8 + jj) * 128 + hidx] = hbuf[jj];
        }
    }
}

// ---------------- Kernel 4: logits + log_softmax, wave per word ------------
extern "C" __global__ void __launch_bounds__(256)
tag_kernel(const float* __restrict__ hs, const float* __restrict__ Wtag,
           const float* __restrict__ btag, float* __restrict__ out)
{
    __shared__ float Wl[64 * 129];
    const int tid = threadIdx.x;
    for (int idx = tid; idx < 64 * 128; idx += 256) {
        int r = idx >> 7, k = idx & 127;
        Wl[r * 129 + k] = Wtag[r * H2 + k];
    }
    __syncthreads();

    const int lane = tid & 63;
    const int word = blockIdx.x * 4 + (tid >> 6);
    const float* hrow = hs + (long)word * H2;
    float acc = btag[lane];
    #pragma unroll 4
    for (int k = 0; k < 128; ++k) acc += Wl[lane * 129 + k] * hrow[k];

    float m = acc;
    #pragma unroll
    for (int off = 32; off > 0; off >>= 1) m = fmaxf(m, __shfl_xor(m, off));
    float e = expf(acc - m);
    float s = e;
    #pragma unroll
    for (int off = 32; off > 0; off >>= 1) s += __shfl_xor(s, off);
    out[(long)word * N_TAGS + lane] = acc - m - logf(s);
}

extern "C" void kernel_launch(void* const* d_in, const int* in_sizes, int n_in,
                              void* d_out, int out_size, void* d_ws, size_t ws_size,
                              hipStream_t stream)
{
    (void)in_sizes; (void)n_in; (void)out_size; (void)ws_size;
    const int*   char_ids  = (const int*)d_in[0];
    const int*   word_ids  = (const int*)d_in[1];
    const int*   char_lens = (const int*)d_in[2];
    const float* char_emb  = (const float*)d_in[3];
    const float* word_emb  = (const float*)d_in[4];
    const float* Wih1 = (const float*)d_in[5];
    const float* Whh1 = (const float*)d_in[6];
    const float* bih1 = (const float*)d_in[7];
    const float* bhh1 = (const float*)d_in[8];
    const float* Wih2 = (const float*)d_in[9];
    const float* Whh2 = (const float*)d_in[10];
    const float* bih2 = (const float*)d_in[11];
    const float* bhh2 = (const float*)d_in[12];
    const float* Wtag = (const float*)d_in[13];
    const float* btag = (const float*)d_in[14];
    float* out = (float*)d_out;

    float* h_char = (float*)d_ws;                          // 16384*64
    float* xpre   = h_char + (size_t)N_WORDS * H1;         // 16384*512 (transposed)
    float* hs     = xpre + (size_t)N_WORDS * 512;          // 16384*128

    const int k1_lds = (256 * 97 + 256 + 16 * 97) * 4;     // 106560 B
    hipFuncSetAttribute((const void*)char_lstm_kernel,
                        hipFuncAttributeMaxDynamicSharedMemorySize, k1_lds);

    char_lstm_kernel<<<N_WORDS / 16, 1024, k1_lds, stream>>>(
        char_ids, char_lens, char_emb, Wih1, Whh1, bih1, bhh1, h_char);

    dim3 g2(N_WORDS / 32, 8);
    xpre_gemm_kernel<<<g2, 256, 0, stream>>>(
        word_ids, word_emb, h_char, Wih2, bih2, bhh2, xpre);

    word_lstm_kernel<<<1, 512, 0, stream>>>(xpre, Whh2, hs);

    tag_kernel<<<N_WORDS / 4, 256, 0, stream>>>(hs, Wtag, btag, out);
}